// Round 1
// baseline (739.878 us; speedup 1.0000x reference)
//
#include <hip/hip_runtime.h>

typedef unsigned short u16;
typedef __attribute__((ext_vector_type(8))) short short8;
typedef __attribute__((ext_vector_type(4))) float f32x4;

__device__ __forceinline__ u16 f2b(float f) {
  union { float f; unsigned u; } c; c.f = f;
  unsigned u = c.u;
  unsigned r = (u + 0x7FFFu + ((u >> 16) & 1u)) >> 16;
  return (u16)r;
}
__device__ __forceinline__ float b2f(u16 h) {
  union { unsigned u; float f; } c; c.u = ((unsigned)h) << 16;
  return c.f;
}

__device__ __forceinline__ void gload16(const u16* g, u16* l) {
  __builtin_amdgcn_global_load_lds((const __attribute__((address_space(1))) void*)g,
                                   (__attribute__((address_space(3))) void*)l, 16, 0, 0);
}

#define MFMA(a, b, c) __builtin_amdgcn_mfma_f32_16x16x32_bf16(a, b, c, 0, 0, 0)

// ---------------- cast fp32 -> bf16 ----------------
__global__ __launch_bounds__(256) void cast_f32_bf16(const float4* __restrict__ in,
                                                     u16* __restrict__ out, int n4) {
  int i = blockIdx.x * 256 + threadIdx.x;
  if (i >= n4) return;
  float4 v = in[i];
  ushort4 r;
  r.x = f2b(v.x); r.y = f2b(v.y); r.z = f2b(v.z); r.w = f2b(v.w);
  *(ushort4*)(out + (size_t)i * 4) = r;
}

// ---------------- RoPE in-place on q,k regions of qkv ----------------
// qkv: [4096][6144] bf16; cols 0..2047 = q, 2048..4095 = k, 4096..6143 = v
__global__ __launch_bounds__(256) void rope_kernel(u16* __restrict__ qkv,
                                                   const float* __restrict__ fc,
                                                   const float* __restrict__ fs) {
  int idx = blockIdx.x * 256 + threadIdx.x;   // 4096 rows * 512 chunks
  int m = idx >> 9;
  int c = idx & 511;                           // 8-elem chunk within cols 0..4095
  int s = m & 2047;
  int colbase = c * 8;
  int i0 = (colbase >> 1) & 63;                // pair index within head, 4 consecutive
  u16* p = qkv + (size_t)m * 6144 + colbase;
  short8 v = *(short8*)p;
  float4 cs = *(const float4*)(fc + (size_t)s * 64 + i0);
  float4 sn = *(const float4*)(fs + (size_t)s * 64 + i0);
  float cc[4] = {cs.x, cs.y, cs.z, cs.w};
  float ss[4] = {sn.x, sn.y, sn.z, sn.w};
#pragma unroll
  for (int t = 0; t < 4; ++t) {
    float x0 = b2f((u16)v[2 * t]);
    float x1 = b2f((u16)v[2 * t + 1]);
    float o0 = x0 * cc[t] - x1 * ss[t];
    float o1 = x0 * ss[t] + x1 * cc[t];
    v[2 * t]     = (short)f2b(o0);
    v[2 * t + 1] = (short)f2b(o1);
  }
  *(short8*)p = v;
}

// ---------------- bf16 NT GEMM: C[M][N] = A[M][K] * B[N][K]^T ----------------
// 128x128 tile, BK=32, 4 waves (2x2), 64x64 per wave, global_load_lds width 16.
template <int F32OUT>
__global__ __launch_bounds__(256) void gemm_nt(const u16* __restrict__ A,
                                               const u16* __restrict__ B,
                                               void* __restrict__ Cp,
                                               int M, int N, int K) {
  __shared__ __align__(16) u16 sA[128 * 32];
  __shared__ __align__(16) u16 sB[128 * 32];
  const int tid = threadIdx.x, l = tid & 63, w = tid >> 6;
  const int nbn = N >> 7;
  const int nwg = (M >> 7) * nbn;
  int bid = blockIdx.x;
  int wg = ((bid & 7) * (nwg >> 3)) + (bid >> 3);   // XCD swizzle (nwg % 8 == 0)
  const int row0 = (wg / nbn) << 7;
  const int col0 = (wg % nbn) << 7;
  const int wr = (w >> 1) * 64, wc = (w & 1) * 64;
  const int ln = l & 15, lk = l >> 4;

  f32x4 acc[4][4];
#pragma unroll
  for (int m = 0; m < 4; ++m)
#pragma unroll
    for (int n = 0; n < 4; ++n) acc[m][n] = (f32x4){0.f, 0.f, 0.f, 0.f};

  for (int k0 = 0; k0 < K; k0 += 32) {
    __syncthreads();
#pragma unroll
    for (int q = 0; q < 2; ++q) {
      int e = w * 2 + q;
      const u16* ga = A + (size_t)(row0 + e * 16 + (l >> 2)) * K + k0 + (l & 3) * 8;
      const u16* gb = B + (size_t)(col0 + e * 16 + (l >> 2)) * K + k0 + (l & 3) * 8;
      gload16(ga, &sA[e * 512]);
      gload16(gb, &sB[e * 512]);
    }
    __syncthreads();
    short8 af[4], bf[4];
#pragma unroll
    for (int m = 0; m < 4; ++m) af[m] = *(const short8*)&sA[(wr + m * 16 + ln) * 32 + lk * 8];
#pragma unroll
    for (int n = 0; n < 4; ++n) bf[n] = *(const short8*)&sB[(wc + n * 16 + ln) * 32 + lk * 8];
#pragma unroll
    for (int m = 0; m < 4; ++m)
#pragma unroll
      for (int n = 0; n < 4; ++n) acc[m][n] = MFMA(af[m], bf[n], acc[m][n]);
  }

#pragma unroll
  for (int m = 0; m < 4; ++m) {
    int r0 = row0 + wr + m * 16 + lk * 4;
#pragma unroll
    for (int n = 0; n < 4; ++n) {
      int c0 = col0 + wc + n * 16 + ln;
#pragma unroll
      for (int j = 0; j < 4; ++j) {
        float v = acc[m][n][j];
        if (F32OUT) ((float*)Cp)[(size_t)(r0 + j) * N + c0] = v;
        else        ((u16*)Cp)[(size_t)(r0 + j) * N + c0]   = f2b(v);
      }
    }
  }
}

// ---------------- flash attention, causal, hd=128, H=16 ----------------
// grid: 1024 = (b*16+h)*32 + qtile ; block 256 (4 waves, 16 Q-rows each)
__global__ __launch_bounds__(256) void attn_fwd(const u16* __restrict__ qkv,
                                                u16* __restrict__ out) {
  __shared__ __align__(16) u16 sK[32 * 128];
  __shared__ __align__(16) u16 sVT[128 * 40];
  __shared__ __align__(16) u16 sP[4][16 * 40];
  const int tid = threadIdx.x, l = tid & 63, w = tid >> 6;
  const int ln = l & 15, lk = l >> 4;
  const int qt = blockIdx.x & 31, bh = blockIdx.x >> 5;
  const int b = bh >> 4, h = bh & 15;
  const int m0 = b * 2048 + qt * 64;
  const u16* Qp = qkv + (size_t)m0 * 6144 + h * 128;
  const u16* Kp = qkv + (size_t)b * 2048 * 6144 + h * 128 + 2048;
  const u16* Vp = Kp + 2048;

  short8 qf[4];
#pragma unroll
  for (int kc = 0; kc < 4; ++kc)
    qf[kc] = *(const short8*)(Qp + (size_t)(w * 16 + ln) * 6144 + kc * 32 + lk * 8);

  f32x4 o[8];
#pragma unroll
  for (int d = 0; d < 8; ++d) o[d] = (f32x4){0.f, 0.f, 0.f, 0.f};
  float mrow[4] = {-1e9f, -1e9f, -1e9f, -1e9f};
  float lsum[4] = {0.f, 0.f, 0.f, 0.f};

  const int ntiles = qt * 2 + 2;
  const float scale = 0.08838834764831845f;  // 1/sqrt(128)

  for (int jt = 0; jt < ntiles; ++jt) {
    __syncthreads();
    // stage K tile [32][128] linear via global_load_lds
#pragma unroll
    for (int q = 0; q < 2; ++q) {
      int e = w * 2 + q;
      const u16* g = Kp + (size_t)(jt * 32 + e * 4 + lk) * 6144 + ln * 8;
      gload16(g, &sK[e * 512]);
    }
    // stage V transposed: sVT[d][j], row stride 40
#pragma unroll
    for (int q = 0; q < 2; ++q) {
      int c = tid + q * 256;
      int jv = c >> 4, d0 = (c & 15) * 8;
      short8 vv = *(const short8*)(Vp + (size_t)(jt * 32 + jv) * 6144 + d0);
#pragma unroll
      for (int i2 = 0; i2 < 8; ++i2) sVT[(d0 + i2) * 40 + jv] = (u16)vv[i2];
    }
    __syncthreads();

    // S = Q K^T (16 rows x 32 cols per wave)
    f32x4 sf[2];
#pragma unroll
    for (int nc = 0; nc < 2; ++nc) {
      f32x4 s = (f32x4){0.f, 0.f, 0.f, 0.f};
#pragma unroll
      for (int kc = 0; kc < 4; ++kc) {
        short8 kb = *(const short8*)&sK[(nc * 16 + ln) * 128 + kc * 32 + lk * 8];
        s = MFMA(qf[kc], kb, s);
      }
      sf[nc] = s;
    }
    // scale + causal mask
    int ig = qt * 64 + w * 16 + lk * 4;
#pragma unroll
    for (int nc = 0; nc < 2; ++nc) {
      int jg = jt * 32 + nc * 16 + ln;
#pragma unroll
      for (int j = 0; j < 4; ++j) {
        float v = sf[nc][j] * scale;
        sf[nc][j] = (jg > ig + j) ? -1e9f : v;
      }
    }
    // row max across 32 cols (16-lane group reduce)
    float tm[4];
#pragma unroll
    for (int j = 0; j < 4; ++j) tm[j] = fmaxf(sf[0][j], sf[1][j]);
#pragma unroll
    for (int off = 1; off < 16; off <<= 1)
#pragma unroll
      for (int j = 0; j < 4; ++j) tm[j] = fmaxf(tm[j], __shfl_xor(tm[j], off, 16));
    float al[4];
#pragma unroll
    for (int j = 0; j < 4; ++j) {
      float mn = fmaxf(mrow[j], tm[j]);
      al[j] = __expf(mrow[j] - mn);
      mrow[j] = mn;
    }
    // P = exp(S - m), row sums; write P (bf16) to per-wave LDS
    float rs[4] = {0.f, 0.f, 0.f, 0.f};
#pragma unroll
    for (int nc = 0; nc < 2; ++nc)
#pragma unroll
      for (int j = 0; j < 4; ++j) {
        float p = __expf(sf[nc][j] - mrow[j]);
        u16 pb = f2b(p);
        sP[w][(lk * 4 + j) * 40 + nc * 16 + ln] = pb;
        rs[j] += b2f(pb);
      }
#pragma unroll
    for (int off = 1; off < 16; off <<= 1)
#pragma unroll
      for (int j = 0; j < 4; ++j) rs[j] += __shfl_xor(rs[j], off, 16);
#pragma unroll
    for (int j = 0; j < 4; ++j) lsum[j] = lsum[j] * al[j] + rs[j];
    // rescale O
#pragma unroll
    for (int d = 0; d < 8; ++d)
#pragma unroll
      for (int j = 0; j < 4; ++j) o[d][j] *= al[j];
    // PV
    short8 pa = *(const short8*)&sP[w][ln * 40 + lk * 8];
#pragma unroll
    for (int d = 0; d < 8; ++d) {
      short8 vb = *(const short8*)&sVT[(d * 16 + ln) * 40 + lk * 8];
      o[d] = MFMA(pa, vb, o[d]);
    }
  }

  float inv[4];
#pragma unroll
  for (int j = 0; j < 4; ++j) inv[j] = 1.f / lsum[j];
#pragma unroll
  for (int d = 0; d < 8; ++d)
#pragma unroll
    for (int j = 0; j < 4; ++j)
      out[(size_t)(m0 + w * 16 + lk * 4 + j) * 2048 + h * 128 + d * 16 + ln] =
          f2b(o[d][j] * inv[j]);
}

extern "C" void kernel_launch(void* const* d_in, const int* in_sizes, int n_in,
                              void* d_out, int out_size, void* d_ws, size_t ws_size,
                              hipStream_t stream) {
  const float* x  = (const float*)d_in[0];
  const float* wq = (const float*)d_in[1];
  const float* wk = (const float*)d_in[2];
  const float* wv = (const float*)d_in[3];
  const float* wo = (const float*)d_in[4];
  const float* fc = (const float*)d_in[5];
  const float* fs = (const float*)d_in[6];
  // d_in[7] = mask — causal handled analytically

  char* ws = (char*)d_ws;
  u16* xb   = (u16*)(ws);                    // 4096x2048 bf16   (16 MB)
  u16* wqkv = (u16*)(ws + 16777216);         // 6144x2048 bf16   (24 MB)
  u16* wob  = (u16*)(ws + 41943040);         // 2048x2048 bf16   (8 MB)
  u16* qkv  = (u16*)(ws + 50331648);         // 4096x6144 bf16   (48 MB)
  u16* aout = (u16*)(ws + 100663296);        // 4096x2048 bf16   (16 MB)

  cast_f32_bf16<<<8192, 256, 0, stream>>>((const float4*)x, xb, 2097152);
  cast_f32_bf16<<<4096, 256, 0, stream>>>((const float4*)wq, wqkv, 1048576);
  cast_f32_bf16<<<4096, 256, 0, stream>>>((const float4*)wk, wqkv + 4194304, 1048576);
  cast_f32_bf16<<<4096, 256, 0, stream>>>((const float4*)wv, wqkv + 8388608, 1048576);
  cast_f32_bf16<<<4096, 256, 0, stream>>>((const float4*)wo, wob, 1048576);

  gemm_nt<0><<<1536, 256, 0, stream>>>(xb, wqkv, qkv, 4096, 6144, 2048);
  rope_kernel<<<8192, 256, 0, stream>>>(qkv, fc, fs);
  attn_fwd<<<1024, 256, 0, stream>>>(qkv, aout);
  gemm_nt<1><<<512, 256, 0, stream>>>(aout, wob, d_out, 4096, 2048, 2048);
}

// Round 2
// 332.580 us; speedup vs baseline: 2.2247x; 2.2247x over previous
//
#include <hip/hip_runtime.h>

typedef unsigned short u16;
typedef __attribute__((ext_vector_type(8))) short short8;
typedef __attribute__((ext_vector_type(4))) short short4s;
typedef __attribute__((ext_vector_type(4))) float f32x4;

__device__ __forceinline__ u16 f2b(float f) {
  union { float f; unsigned u; } c; c.f = f;
  unsigned u = c.u;
  unsigned r = (u + 0x7FFFu + ((u >> 16) & 1u)) >> 16;
  return (u16)r;
}
__device__ __forceinline__ float b2f(u16 h) {
  union { unsigned u; float f; } c; c.u = ((unsigned)h) << 16;
  return c.f;
}

__device__ __forceinline__ void gload16(const u16* g, u16* l) {
  __builtin_amdgcn_global_load_lds((const __attribute__((address_space(1))) void*)g,
                                   (__attribute__((address_space(3))) void*)l, 16, 0, 0);
}

__device__ __forceinline__ short4s tr16(const u16* p) {
  short4s d;
  asm volatile("ds_read_b64_tr_b16 %0, %1"
               : "=v"(d)
               : "v"((const __attribute__((address_space(3))) u16*)p));
  return d;
}

#define MFMA(a, b, c) __builtin_amdgcn_mfma_f32_16x16x32_bf16(a, b, c, 0, 0, 0)

// ---------------- cast fp32 -> bf16 ----------------
__global__ __launch_bounds__(256) void cast_f32_bf16(const float4* __restrict__ in,
                                                     u16* __restrict__ out, int n4) {
  int i = blockIdx.x * 256 + threadIdx.x;
  if (i >= n4) return;
  float4 v = in[i];
  ushort4 r;
  r.x = f2b(v.x); r.y = f2b(v.y); r.z = f2b(v.z); r.w = f2b(v.w);
  *(ushort4*)(out + (size_t)i * 4) = r;
}

// ---------------- RoPE in-place on q,k regions of qkv ----------------
__global__ __launch_bounds__(256) void rope_kernel(u16* __restrict__ qkv,
                                                   const float* __restrict__ fc,
                                                   const float* __restrict__ fs) {
  int idx = blockIdx.x * 256 + threadIdx.x;
  int m = idx >> 9;
  int c = idx & 511;
  int s = m & 2047;
  int colbase = c * 8;
  int i0 = (colbase >> 1) & 63;
  u16* p = qkv + (size_t)m * 6144 + colbase;
  short8 v = *(short8*)p;
  float4 cs = *(const float4*)(fc + (size_t)s * 64 + i0);
  float4 sn = *(const float4*)(fs + (size_t)s * 64 + i0);
  float cc[4] = {cs.x, cs.y, cs.z, cs.w};
  float ss[4] = {sn.x, sn.y, sn.z, sn.w};
#pragma unroll
  for (int t = 0; t < 4; ++t) {
    float x0 = b2f((u16)v[2 * t]);
    float x1 = b2f((u16)v[2 * t + 1]);
    float o0 = x0 * cc[t] - x1 * ss[t];
    float o1 = x0 * ss[t] + x1 * cc[t];
    v[2 * t]     = (short)f2b(o0);
    v[2 * t + 1] = (short)f2b(o1);
  }
  *(short8*)p = v;
}

// ---------------- bf16 NT GEMM: C[M][N] = A[M][K] * B[N][K]^T ----------------
template <int F32OUT>
__global__ __launch_bounds__(256) void gemm_nt(const u16* __restrict__ A,
                                               const u16* __restrict__ B,
                                               void* __restrict__ Cp,
                                               int M, int N, int K) {
  __shared__ __align__(16) u16 sA[128 * 32];
  __shared__ __align__(16) u16 sB[128 * 32];
  const int tid = threadIdx.x, l = tid & 63, w = tid >> 6;
  const int nbn = N >> 7;
  const int nwg = (M >> 7) * nbn;
  int bid = blockIdx.x;
  int wg = ((bid & 7) * (nwg >> 3)) + (bid >> 3);
  const int row0 = (wg / nbn) << 7;
  const int col0 = (wg % nbn) << 7;
  const int wr = (w >> 1) * 64, wc = (w & 1) * 64;
  const int ln = l & 15, lk = l >> 4;

  f32x4 acc[4][4];
#pragma unroll
  for (int m = 0; m < 4; ++m)
#pragma unroll
    for (int n = 0; n < 4; ++n) acc[m][n] = (f32x4){0.f, 0.f, 0.f, 0.f};

  for (int k0 = 0; k0 < K; k0 += 32) {
    __syncthreads();
#pragma unroll
    for (int q = 0; q < 2; ++q) {
      int e = w * 2 + q;
      const u16* ga = A + (size_t)(row0 + e * 16 + (l >> 2)) * K + k0 + (l & 3) * 8;
      const u16* gb = B + (size_t)(col0 + e * 16 + (l >> 2)) * K + k0 + (l & 3) * 8;
      gload16(ga, &sA[e * 512]);
      gload16(gb, &sB[e * 512]);
    }
    __syncthreads();
    short8 af[4], bf[4];
#pragma unroll
    for (int m = 0; m < 4; ++m) af[m] = *(const short8*)&sA[(wr + m * 16 + ln) * 32 + lk * 8];
#pragma unroll
    for (int n = 0; n < 4; ++n) bf[n] = *(const short8*)&sB[(wc + n * 16 + ln) * 32 + lk * 8];
#pragma unroll
    for (int m = 0; m < 4; ++m)
#pragma unroll
      for (int n = 0; n < 4; ++n) acc[m][n] = MFMA(af[m], bf[n], acc[m][n]);
  }

#pragma unroll
  for (int m = 0; m < 4; ++m) {
    int r0 = row0 + wr + m * 16 + lk * 4;
#pragma unroll
    for (int n = 0; n < 4; ++n) {
      int c0 = col0 + wc + n * 16 + ln;
#pragma unroll
      for (int j = 0; j < 4; ++j) {
        float v = acc[m][n][j];
        if (F32OUT) ((float*)Cp)[(size_t)(r0 + j) * N + c0] = v;
        else        ((u16*)Cp)[(size_t)(r0 + j) * N + c0]   = f2b(v);
      }
    }
  }
}

// ---------------- flash attention v2: causal, hd=128, H=16 ----------------
// 512 blocks; block bh handles q-tiles {pr, 31-pr} (64 rows each) -> 33 KV
// tiles of 64 per block (perfect balance). 4 waves x 16 Q-rows.
// sK: [64][128] XOR-swizzled (chunk^=(row&7)) staged via pre-swizzled source.
// sV: subtiled [j/4][d/16][4][16] for ds_read_b64_tr_b16 consumption.
__global__ __launch_bounds__(256) void attn_fwd(const u16* __restrict__ qkv,
                                                u16* __restrict__ out) {
  __shared__ __align__(16) u16 sK[2][64 * 128];
  __shared__ __align__(16) u16 sV[2][64 * 128];
  __shared__ __align__(16) u16 sP[4][16 * 72];
  const int tid = threadIdx.x, l = tid & 63, w = tid >> 6;
  const int ln = l & 15, lk = l >> 4;

  const int bid = blockIdx.x;
  const int l0 = ((bid & 7) << 6) + (bid >> 3);   // XCD-cluster: same bh on one XCD
  const int bh = l0 >> 4, pr = l0 & 15;
  const int b = bh >> 4, h = bh & 15;

  const u16* Kp = qkv + (size_t)b * 2048 * 6144 + 2048 + h * 128;
  const u16* Vp = Kp + 2048;
  const float scale = 0.08838834764831845f;  // 1/sqrt(128)

  for (int pass = 0; pass < 2; ++pass) {
    const int qt = pass ? (31 - pr) : pr;
    const int m0 = b * 2048 + qt * 64;
    const u16* Qp = qkv + (size_t)m0 * 6144 + h * 128;

    short8 qf[4];
#pragma unroll
    for (int kc = 0; kc < 4; ++kc)
      qf[kc] = *(const short8*)(Qp + (size_t)(w * 16 + ln) * 6144 + kc * 32 + lk * 8);

    f32x4 o[8];
#pragma unroll
    for (int d = 0; d < 8; ++d) o[d] = (f32x4){0.f, 0.f, 0.f, 0.f};
    float mrow[4] = {-1e9f, -1e9f, -1e9f, -1e9f};
    float lsum[4] = {0.f, 0.f, 0.f, 0.f};

    const int ntl = qt + 1;

    // prologue: stage tile 0 into buffer 0
    {
      const u16* Kt = Kp;
      const u16* Vt = Vp;
#pragma unroll
      for (int q = 0; q < 4; ++q) {
        int e = q * 256 + tid;
        int r = e >> 4, p = e & 15;
        gload16(Kt + (size_t)r * 6144 + ((p ^ (r & 7)) << 3), &sK[0][e * 8]);
        int j = ((e >> 6) << 2) + ((e & 7) >> 1);
        int d = (((e >> 3) & 7) << 4) + ((e & 1) << 3);
        gload16(Vt + (size_t)j * 6144 + d, &sV[0][e * 8]);
      }
    }
    __syncthreads();

    int cur = 0;
    for (int jt = 0; jt < ntl; ++jt) {
      // issue next tile's staging early (hidden under compute)
      if (jt + 1 < ntl) {
        const u16* Kt = Kp + (size_t)(jt + 1) * 64 * 6144;
        const u16* Vt = Vp + (size_t)(jt + 1) * 64 * 6144;
        int nb = cur ^ 1;
#pragma unroll
        for (int q = 0; q < 4; ++q) {
          int e = q * 256 + tid;
          int r = e >> 4, p = e & 15;
          gload16(Kt + (size_t)r * 6144 + ((p ^ (r & 7)) << 3), &sK[nb][e * 8]);
          int j = ((e >> 6) << 2) + ((e & 7) >> 1);
          int d = (((e >> 3) & 7) << 4) + ((e & 1) << 3);
          gload16(Vt + (size_t)j * 6144 + d, &sV[nb][e * 8]);
        }
      }

      // ---- QK^T: 16 rows x 64 cols per wave ----
      f32x4 sf[4];
#pragma unroll
      for (int nc = 0; nc < 4; ++nc) {
        f32x4 s = (f32x4){0.f, 0.f, 0.f, 0.f};
#pragma unroll
        for (int kc = 0; kc < 4; ++kc) {
          int r = nc * 16 + ln;
          short8 kb = *(const short8*)&sK[cur][r * 128 + (((kc << 2) + lk) ^ (r & 7)) * 8];
          s = MFMA(qf[kc], kb, s);
        }
        sf[nc] = s;
      }

      // scale (+ causal mask on diagonal tile only)
      if (jt == qt) {
        int ig = w * 16 + lk * 4;
#pragma unroll
        for (int nc = 0; nc < 4; ++nc) {
          int jg = nc * 16 + ln;
#pragma unroll
          for (int j = 0; j < 4; ++j)
            sf[nc][j] = (jg > ig + j) ? -1e9f : sf[nc][j] * scale;
        }
      } else {
#pragma unroll
        for (int nc = 0; nc < 4; ++nc)
#pragma unroll
          for (int j = 0; j < 4; ++j) sf[nc][j] *= scale;
      }

      // ---- online softmax ----
      float tm[4];
#pragma unroll
      for (int j = 0; j < 4; ++j)
        tm[j] = fmaxf(fmaxf(sf[0][j], sf[1][j]), fmaxf(sf[2][j], sf[3][j]));
#pragma unroll
      for (int off = 1; off < 16; off <<= 1)
#pragma unroll
        for (int j = 0; j < 4; ++j) tm[j] = fmaxf(tm[j], __shfl_xor(tm[j], off, 16));
      float al[4];
#pragma unroll
      for (int j = 0; j < 4; ++j) {
        float mn = fmaxf(mrow[j], tm[j]);
        al[j] = __expf(mrow[j] - mn);
        mrow[j] = mn;
      }
      float rs[4] = {0.f, 0.f, 0.f, 0.f};
#pragma unroll
      for (int nc = 0; nc < 4; ++nc)
#pragma unroll
        for (int j = 0; j < 4; ++j) {
          float p = __expf(sf[nc][j] - mrow[j]);
          u16 pb = f2b(p);
          sP[w][(lk * 4 + j) * 72 + nc * 16 + ln] = pb;
          rs[j] += b2f(pb);
        }
#pragma unroll
      for (int off = 1; off < 16; off <<= 1)
#pragma unroll
        for (int j = 0; j < 4; ++j) rs[j] += __shfl_xor(rs[j], off, 16);
#pragma unroll
      for (int j = 0; j < 4; ++j) lsum[j] = lsum[j] * al[j] + rs[j];
#pragma unroll
      for (int d = 0; d < 8; ++d)
#pragma unroll
        for (int j = 0; j < 4; ++j) o[d][j] *= al[j];

      // ---- PV via hardware transpose reads of subtiled sV ----
      short8 pa0 = *(const short8*)&sP[w][ln * 72 + lk * 8];
      short8 pa1 = *(const short8*)&sP[w][ln * 72 + 32 + lk * 8];
#pragma unroll
      for (int dblk = 0; dblk < 8; ++dblk) {
        const u16* b0 = &sV[cur][(lk * 2) * 512 + dblk * 64 + ln * 4];
        const u16* b1 = b0 + 8 * 512;
        short4s t00 = tr16(b0);
        short4s t01 = tr16(b0 + 512);
        short4s t10 = tr16(b1);
        short4s t11 = tr16(b1 + 512);
        asm volatile("s_waitcnt lgkmcnt(0)" ::: "memory");
        __builtin_amdgcn_sched_barrier(0);
        short8 vb0 = {t00[0], t00[1], t00[2], t00[3], t01[0], t01[1], t01[2], t01[3]};
        short8 vb1 = {t10[0], t10[1], t10[2], t10[3], t11[0], t11[1], t11[2], t11[3]};
        o[dblk] = MFMA(pa0, vb0, o[dblk]);
        o[dblk] = MFMA(pa1, vb1, o[dblk]);
      }

      __syncthreads();
      cur ^= 1;
    }

    float inv[4];
#pragma unroll
    for (int j = 0; j < 4; ++j) inv[j] = 1.f / lsum[j];
#pragma unroll
    for (int d = 0; d < 8; ++d)
#pragma unroll
      for (int j = 0; j < 4; ++j)
        out[(size_t)(m0 + w * 16 + lk * 4 + j) * 2048 + h * 128 + d * 16 + ln] =
            f2b(o[d][j] * inv[j]);
  }
}

extern "C" void kernel_launch(void* const* d_in, const int* in_sizes, int n_in,
                              void* d_out, int out_size, void* d_ws, size_t ws_size,
                              hipStream_t stream) {
  const float* x  = (const float*)d_in[0];
  const float* wq = (const float*)d_in[1];
  const float* wk = (const float*)d_in[2];
  const float* wv = (const float*)d_in[3];
  const float* wo = (const float*)d_in[4];
  const float* fc = (const float*)d_in[5];
  const float* fs = (const float*)d_in[6];

  char* ws = (char*)d_ws;
  u16* xb   = (u16*)(ws);
  u16* wqkv = (u16*)(ws + 16777216);
  u16* wob  = (u16*)(ws + 41943040);
  u16* qkv  = (u16*)(ws + 50331648);
  u16* aout = (u16*)(ws + 100663296);

  cast_f32_bf16<<<8192, 256, 0, stream>>>((const float4*)x, xb, 2097152);
  cast_f32_bf16<<<4096, 256, 0, stream>>>((const float4*)wq, wqkv, 1048576);
  cast_f32_bf16<<<4096, 256, 0, stream>>>((const float4*)wk, wqkv + 4194304, 1048576);
  cast_f32_bf16<<<4096, 256, 0, stream>>>((const float4*)wv, wqkv + 8388608, 1048576);
  cast_f32_bf16<<<4096, 256, 0, stream>>>((const float4*)wo, wob, 1048576);

  gemm_nt<0><<<1536, 256, 0, stream>>>(xb, wqkv, qkv, 4096, 6144, 2048);
  rope_kernel<<<8192, 256, 0, stream>>>(qkv, fc, fs);
  attn_fwd<<<512, 256, 0, stream>>>(qkv, aout);
  gemm_nt<1><<<512, 256, 0, stream>>>(aout, wob, d_out, 4096, 2048, 2048);
}

// Round 3
// 303.544 us; speedup vs baseline: 2.4375x; 1.0957x over previous
//
#include <hip/hip_runtime.h>

typedef unsigned short u16;
typedef __attribute__((ext_vector_type(8))) short short8;
typedef __attribute__((ext_vector_type(4))) short short4s;
typedef __attribute__((ext_vector_type(4))) float f32x4;

__device__ __forceinline__ u16 f2b(float f) {
  union { float f; unsigned u; } c; c.f = f;
  unsigned u = c.u;
  unsigned r = (u + 0x7FFFu + ((u >> 16) & 1u)) >> 16;
  return (u16)r;
}
__device__ __forceinline__ float b2f(u16 h) {
  union { unsigned u; float f; } c; c.u = ((unsigned)h) << 16;
  return c.f;
}

__device__ __forceinline__ void gload16(const u16* g, u16* l) {
  __builtin_amdgcn_global_load_lds((const __attribute__((address_space(1))) void*)g,
                                   (__attribute__((address_space(3))) void*)l, 16, 0, 0);
}

__device__ __forceinline__ short4s tr16(const u16* p) {
  short4s d;
  asm volatile("ds_read_b64_tr_b16 %0, %1"
               : "=v"(d)
               : "v"((const __attribute__((address_space(3))) u16*)p));
  return d;
}

#define MFMA(a, b, c) __builtin_amdgcn_mfma_f32_16x16x32_bf16(a, b, c, 0, 0, 0)

// ---------------- cast fp32 -> bf16 ----------------
__global__ __launch_bounds__(256) void cast_f32_bf16(const float4* __restrict__ in,
                                                     u16* __restrict__ out, int n4) {
  int i = blockIdx.x * 256 + threadIdx.x;
  if (i >= n4) return;
  float4 v = in[i];
  ushort4 r;
  r.x = f2b(v.x); r.y = f2b(v.y); r.z = f2b(v.z); r.w = f2b(v.w);
  *(ushort4*)(out + (size_t)i * 4) = r;
}

// ---------------- RoPE in-place on q,k regions of qkv ----------------
__global__ __launch_bounds__(256) void rope_kernel(u16* __restrict__ qkv,
                                                   const float* __restrict__ fc,
                                                   const float* __restrict__ fs) {
  int idx = blockIdx.x * 256 + threadIdx.x;
  int m = idx >> 9;
  int c = idx & 511;
  int s = m & 2047;
  int colbase = c * 8;
  int i0 = (colbase >> 1) & 63;
  u16* p = qkv + (size_t)m * 6144 + colbase;
  short8 v = *(short8*)p;
  float4 cs = *(const float4*)(fc + (size_t)s * 64 + i0);
  float4 sn = *(const float4*)(fs + (size_t)s * 64 + i0);
  float cc[4] = {cs.x, cs.y, cs.z, cs.w};
  float ss[4] = {sn.x, sn.y, sn.z, sn.w};
#pragma unroll
  for (int t = 0; t < 4; ++t) {
    float x0 = b2f((u16)v[2 * t]);
    float x1 = b2f((u16)v[2 * t + 1]);
    float o0 = x0 * cc[t] - x1 * ss[t];
    float o1 = x0 * ss[t] + x1 * cc[t];
    v[2 * t]     = (short)f2b(o0);
    v[2 * t + 1] = (short)f2b(o1);
  }
  *(short8*)p = v;
}

// ---------------- 256x256 8-phase bf16 NT GEMM ----------------
// C[M][N] = A[M][K] * B[N][K]^T, BK=64, 512 thr = 8 waves (2M x 4N),
// per-wave C 128x64. LDS 128 KiB: [A|B][dbuf][half 128x64] XOR-swizzled.
// Schedule per K-tile t (4 phases, quadrant q): ds_read frags (B all at q0,
// A quadrant per phase); stage q0/q1 -> A(t+1), q2/q3 -> B(t+2); counted
// vmcnt(4) at q3; 2 raw barriers per phase around the 16-MFMA cluster.
template <int F32OUT>
__global__ __launch_bounds__(512, 2) void gemm_nt_8ph(const u16* __restrict__ Ag,
                                                      const u16* __restrict__ Bg,
                                                      void* __restrict__ Cp,
                                                      int M, int N, int K) {
  __shared__ __align__(16) u16 lds[65536];
  const int tid = threadIdx.x;
  const int l = tid & 63, w = tid >> 6;
  const int wm = w >> 2, wn = w & 3;
  const int ln = l & 15, lk = l >> 4;
  const int nbn = N >> 8;
  const int nwg = (M >> 8) * nbn;
  const int wg = ((blockIdx.x & 7) * (nwg >> 3)) + (blockIdx.x >> 3);
  const int row0 = (wg / nbn) << 8;
  const int col0 = (wg % nbn) << 8;
  const int T = K >> 6;

  // staging coords: thread handles chunks e0,e1 of each 16KB half-tile
  const int e0 = tid, e1 = 512 + tid;
  const int r0s = e0 >> 3, j0s = (e0 & 7) ^ (r0s & 7);
  const int r1s = e1 >> 3, j1s = (e1 & 7) ^ (r1s & 7);

#define STAGE_A(t, h)                                                                 \
  {                                                                                   \
    u16* dst = lds + ((t) & 1) * 16384 + (h) * 8192;                                  \
    gload16(Ag + (size_t)(row0 + (h) * 128 + r0s) * K + (t) * 64 + (j0s << 3),        \
            dst + e0 * 8);                                                            \
    gload16(Ag + (size_t)(row0 + (h) * 128 + r1s) * K + (t) * 64 + (j1s << 3),        \
            dst + e1 * 8);                                                            \
  }
#define STAGE_B(t, h)                                                                 \
  {                                                                                   \
    u16* dst = lds + 32768 + ((t) & 1) * 16384 + (h) * 8192;                          \
    gload16(Bg + (size_t)(col0 + (h) * 128 + r0s) * K + (t) * 64 + (j0s << 3),        \
            dst + e0 * 8);                                                            \
    gload16(Bg + (size_t)(col0 + (h) * 128 + r1s) * K + (t) * 64 + (j1s << 3),        \
            dst + e1 * 8);                                                            \
  }

  f32x4 acc[8][4];
#pragma unroll
  for (int m = 0; m < 8; ++m)
#pragma unroll
    for (int n = 0; n < 4; ++n) acc[m][n] = (f32x4){0.f, 0.f, 0.f, 0.f};

  // fragment LDS offsets (u16 units); row&7 == ln&7 for all frags
  const int x = ln & 7;
  // A frag (m,kk): (m*16+ln)*64 + (((kk*4+lk)^x)<<3)
  // B frag (n,kk): ((wn&1)*64+n*16+ln)*64 + (((kk*4+lk)^x)<<3)
  const int c0 = ((lk ^ x) << 3), c1 = (((4 + lk) ^ x) << 3);

  // prologue: tiles 0,1 fully staged
  STAGE_A(0, 0); STAGE_A(0, 1); STAGE_B(0, 0); STAGE_B(0, 1);
  STAGE_A(1, 0); STAGE_A(1, 1); STAGE_B(1, 0); STAGE_B(1, 1);
  asm volatile("s_waitcnt vmcnt(8)" ::: "memory");
  __builtin_amdgcn_s_barrier();

  for (int t = 0; t < T; ++t) {
    const u16* aB = lds + (t & 1) * 16384 + wm * 8192;
    const u16* bB = lds + 32768 + (t & 1) * 16384 + (wn >> 1) * 8192;
    short8 bf[4][2];
    short8 af[2][2];
#pragma unroll
    for (int q = 0; q < 4; ++q) {
      // ---- register loads for THIS phase's MFMA ----
      if (q == 0) {
#pragma unroll
        for (int n = 0; n < 4; ++n) {
          int rb = ((wn & 1) * 64 + n * 16 + ln) * 64;
          bf[n][0] = *(const short8*)&bB[rb + c0];
          bf[n][1] = *(const short8*)&bB[rb + c1];
        }
      }
#pragma unroll
      for (int m2 = 0; m2 < 2; ++m2) {
        int ra = ((q * 2 + m2) * 16 + ln) * 64;
        af[m2][0] = *(const short8*)&aB[ra + c0];
        af[m2][1] = *(const short8*)&aB[ra + c1];
      }
      // ---- stage schedule ----
      if (q == 0) { if (t >= 1 && t + 1 < T) STAGE_A(t + 1, 0); }
      else if (q == 1) { if (t >= 1 && t + 1 < T) STAGE_A(t + 1, 1); }
      else if (q == 2) { if (t + 2 < T) STAGE_B(t + 2, 0); }
      else {
        if (t + 2 < T) {
          STAGE_B(t + 2, 1);
          asm volatile("s_waitcnt vmcnt(4)" ::: "memory");
        } else {
          asm volatile("s_waitcnt vmcnt(0)" ::: "memory");
        }
      }
      __builtin_amdgcn_sched_barrier(0);
      __builtin_amdgcn_s_barrier();
      __builtin_amdgcn_sched_barrier(0);
      __builtin_amdgcn_s_setprio(1);
#pragma unroll
      for (int m2 = 0; m2 < 2; ++m2)
#pragma unroll
        for (int n = 0; n < 4; ++n)
#pragma unroll
          for (int kk = 0; kk < 2; ++kk)
            acc[q * 2 + m2][n] = MFMA(af[m2][kk], bf[n][kk], acc[q * 2 + m2][n]);
      __builtin_amdgcn_s_setprio(0);
      __builtin_amdgcn_sched_barrier(0);
      __builtin_amdgcn_s_barrier();
      __builtin_amdgcn_sched_barrier(0);
    }
  }

#pragma unroll
  for (int m = 0; m < 8; ++m) {
    int r0 = row0 + wm * 128 + m * 16 + lk * 4;
#pragma unroll
    for (int n = 0; n < 4; ++n) {
      int cc = col0 + wn * 64 + n * 16 + ln;
#pragma unroll
      for (int j = 0; j < 4; ++j) {
        float v = acc[m][n][j];
        if (F32OUT) ((float*)Cp)[(size_t)(r0 + j) * N + cc] = v;
        else        ((u16*)Cp)[(size_t)(r0 + j) * N + cc]   = f2b(v);
      }
    }
  }
#undef STAGE_A
#undef STAGE_B
}

// ---------------- m97-style 128x128 NT GEMM (kept for gemm2) ----------------
template <int F32OUT>
__global__ __launch_bounds__(256) void gemm_nt(const u16* __restrict__ A,
                                               const u16* __restrict__ B,
                                               void* __restrict__ Cp,
                                               int M, int N, int K) {
  __shared__ __align__(16) u16 sA[128 * 32];
  __shared__ __align__(16) u16 sB[128 * 32];
  const int tid = threadIdx.x, l = tid & 63, w = tid >> 6;
  const int nbn = N >> 7;
  const int nwg = (M >> 7) * nbn;
  int bid = blockIdx.x;
  int wg = ((bid & 7) * (nwg >> 3)) + (bid >> 3);
  const int row0 = (wg / nbn) << 7;
  const int col0 = (wg % nbn) << 7;
  const int wr = (w >> 1) * 64, wc = (w & 1) * 64;
  const int ln = l & 15, lk = l >> 4;

  f32x4 acc[4][4];
#pragma unroll
  for (int m = 0; m < 4; ++m)
#pragma unroll
    for (int n = 0; n < 4; ++n) acc[m][n] = (f32x4){0.f, 0.f, 0.f, 0.f};

  for (int k0 = 0; k0 < K; k0 += 32) {
    __syncthreads();
#pragma unroll
    for (int q = 0; q < 2; ++q) {
      int e = w * 2 + q;
      const u16* ga = A + (size_t)(row0 + e * 16 + (l >> 2)) * K + k0 + (l & 3) * 8;
      const u16* gb = B + (size_t)(col0 + e * 16 + (l >> 2)) * K + k0 + (l & 3) * 8;
      gload16(ga, &sA[e * 512]);
      gload16(gb, &sB[e * 512]);
    }
    __syncthreads();
    short8 af[4], bf[4];
#pragma unroll
    for (int m = 0; m < 4; ++m) af[m] = *(const short8*)&sA[(wr + m * 16 + ln) * 32 + lk * 8];
#pragma unroll
    for (int n = 0; n < 4; ++n) bf[n] = *(const short8*)&sB[(wc + n * 16 + ln) * 32 + lk * 8];
#pragma unroll
    for (int m = 0; m < 4; ++m)
#pragma unroll
      for (int n = 0; n < 4; ++n) acc[m][n] = MFMA(af[m], bf[n], acc[m][n]);
  }

#pragma unroll
  for (int m = 0; m < 4; ++m) {
    int r0 = row0 + wr + m * 16 + lk * 4;
#pragma unroll
    for (int n = 0; n < 4; ++n) {
      int c0 = col0 + wc + n * 16 + ln;
#pragma unroll
      for (int j = 0; j < 4; ++j) {
        float v = acc[m][n][j];
        if (F32OUT) ((float*)Cp)[(size_t)(r0 + j) * N + c0] = v;
        else        ((u16*)Cp)[(size_t)(r0 + j) * N + c0]   = f2b(v);
      }
    }
  }
}

// ---------------- flash attention: causal, hd=128, H=16 ----------------
__global__ __launch_bounds__(256) void attn_fwd(const u16* __restrict__ qkv,
                                                u16* __restrict__ out) {
  __shared__ __align__(16) u16 sK[2][64 * 128];
  __shared__ __align__(16) u16 sV[2][64 * 128];
  __shared__ __align__(16) u16 sP[4][16 * 72];
  const int tid = threadIdx.x, l = tid & 63, w = tid >> 6;
  const int ln = l & 15, lk = l >> 4;

  const int bid = blockIdx.x;
  const int l0 = ((bid & 7) << 6) + (bid >> 3);
  const int bh = l0 >> 4, pr = l0 & 15;
  const int b = bh >> 4, h = bh & 15;

  const u16* Kp = qkv + (size_t)b * 2048 * 6144 + 2048 + h * 128;
  const u16* Vp = Kp + 2048;
  const float scale = 0.08838834764831845f;

  for (int pass = 0; pass < 2; ++pass) {
    const int qt = pass ? (31 - pr) : pr;
    const int m0 = b * 2048 + qt * 64;
    const u16* Qp = qkv + (size_t)m0 * 6144 + h * 128;

    short8 qf[4];
#pragma unroll
    for (int kc = 0; kc < 4; ++kc)
      qf[kc] = *(const short8*)(Qp + (size_t)(w * 16 + ln) * 6144 + kc * 32 + lk * 8);

    f32x4 o[8];
#pragma unroll
    for (int d = 0; d < 8; ++d) o[d] = (f32x4){0.f, 0.f, 0.f, 0.f};
    float mrow[4] = {-1e9f, -1e9f, -1e9f, -1e9f};
    float lsum[4] = {0.f, 0.f, 0.f, 0.f};

    const int ntl = qt + 1;

    {
      const u16* Kt = Kp;
      const u16* Vt = Vp;
#pragma unroll
      for (int q = 0; q < 4; ++q) {
        int e = q * 256 + tid;
        int r = e >> 4, p = e & 15;
        gload16(Kt + (size_t)r * 6144 + ((p ^ (r & 7)) << 3), &sK[0][e * 8]);
        int j = ((e >> 6) << 2) + ((e & 7) >> 1);
        int d = (((e >> 3) & 7) << 4) + ((e & 1) << 3);
        gload16(Vt + (size_t)j * 6144 + d, &sV[0][e * 8]);
      }
    }
    __syncthreads();

    int cur = 0;
    for (int jt = 0; jt < ntl; ++jt) {
      if (jt + 1 < ntl) {
        const u16* Kt = Kp + (size_t)(jt + 1) * 64 * 6144;
        const u16* Vt = Vp + (size_t)(jt + 1) * 64 * 6144;
        int nb = cur ^ 1;
#pragma unroll
        for (int q = 0; q < 4; ++q) {
          int e = q * 256 + tid;
          int r = e >> 4, p = e & 15;
          gload16(Kt + (size_t)r * 6144 + ((p ^ (r & 7)) << 3), &sK[nb][e * 8]);
          int j = ((e >> 6) << 2) + ((e & 7) >> 1);
          int d = (((e >> 3) & 7) << 4) + ((e & 1) << 3);
          gload16(Vt + (size_t)j * 6144 + d, &sV[nb][e * 8]);
        }
      }

      f32x4 sf[4];
#pragma unroll
      for (int nc = 0; nc < 4; ++nc) {
        f32x4 s = (f32x4){0.f, 0.f, 0.f, 0.f};
#pragma unroll
        for (int kc = 0; kc < 4; ++kc) {
          int r = nc * 16 + ln;
          short8 kb = *(const short8*)&sK[cur][r * 128 + (((kc << 2) + lk) ^ (r & 7)) * 8];
          s = MFMA(qf[kc], kb, s);
        }
        sf[nc] = s;
      }

      if (jt == qt) {
        int ig = w * 16 + lk * 4;
#pragma unroll
        for (int nc = 0; nc < 4; ++nc) {
          int jg = nc * 16 + ln;
#pragma unroll
          for (int j = 0; j < 4; ++j)
            sf[nc][j] = (jg > ig + j) ? -1e9f : sf[nc][j] * scale;
        }
      } else {
#pragma unroll
        for (int nc = 0; nc < 4; ++nc)
#pragma unroll
          for (int j = 0; j < 4; ++j) sf[nc][j] *= scale;
      }

      float tm[4];
#pragma unroll
      for (int j = 0; j < 4; ++j)
        tm[j] = fmaxf(fmaxf(sf[0][j], sf[1][j]), fmaxf(sf[2][j], sf[3][j]));
#pragma unroll
      for (int off = 1; off < 16; off <<= 1)
#pragma unroll
        for (int j = 0; j < 4; ++j) tm[j] = fmaxf(tm[j], __shfl_xor(tm[j], off, 16));
      float al[4];
#pragma unroll
      for (int j = 0; j < 4; ++j) {
        float mn = fmaxf(mrow[j], tm[j]);
        al[j] = __expf(mrow[j] - mn);
        mrow[j] = mn;
      }
      float rs[4] = {0.f, 0.f, 0.f, 0.f};
#pragma unroll
      for (int nc = 0; nc < 4; ++nc)
#pragma unroll
        for (int j = 0; j < 4; ++j) {
          float p = __expf(sf[nc][j] - mrow[j]);
          u16 pb = f2b(p);
          sP[w][(lk * 4 + j) * 72 + nc * 16 + ln] = pb;
          rs[j] += b2f(pb);
        }
#pragma unroll
      for (int off = 1; off < 16; off <<= 1)
#pragma unroll
        for (int j = 0; j < 4; ++j) rs[j] += __shfl_xor(rs[j], off, 16);
#pragma unroll
      for (int j = 0; j < 4; ++j) lsum[j] = lsum[j] * al[j] + rs[j];
#pragma unroll
      for (int d = 0; d < 8; ++d)
#pragma unroll
        for (int j = 0; j < 4; ++j) o[d][j] *= al[j];

      short8 pa0 = *(const short8*)&sP[w][ln * 72 + lk * 8];
      short8 pa1 = *(const short8*)&sP[w][ln * 72 + 32 + lk * 8];
#pragma unroll
      for (int dblk = 0; dblk < 8; ++dblk) {
        const u16* b0 = &sV[cur][(lk * 2) * 512 + dblk * 64 + ln * 4];
        const u16* b1 = b0 + 8 * 512;
        short4s t00 = tr16(b0);
        short4s t01 = tr16(b0 + 512);
        short4s t10 = tr16(b1);
        short4s t11 = tr16(b1 + 512);
        asm volatile("s_waitcnt lgkmcnt(0)" ::: "memory");
        __builtin_amdgcn_sched_barrier(0);
        short8 vb0 = {t00[0], t00[1], t00[2], t00[3], t01[0], t01[1], t01[2], t01[3]};
        short8 vb1 = {t10[0], t10[1], t10[2], t10[3], t11[0], t11[1], t11[2], t11[3]};
        o[dblk] = MFMA(pa0, vb0, o[dblk]);
        o[dblk] = MFMA(pa1, vb1, o[dblk]);
      }

      __syncthreads();
      cur ^= 1;
    }

    float inv[4];
#pragma unroll
    for (int j = 0; j < 4; ++j) inv[j] = 1.f / lsum[j];
#pragma unroll
    for (int d = 0; d < 8; ++d)
#pragma unroll
      for (int j = 0; j < 4; ++j)
        out[(size_t)(m0 + w * 16 + lk * 4 + j) * 2048 + h * 128 + d * 16 + ln] =
            f2b(o[d][j] * inv[j]);
  }
}

extern "C" void kernel_launch(void* const* d_in, const int* in_sizes, int n_in,
                              void* d_out, int out_size, void* d_ws, size_t ws_size,
                              hipStream_t stream) {
  const float* x  = (const float*)d_in[0];
  const float* wq = (const float*)d_in[1];
  const float* wk = (const float*)d_in[2];
  const float* wv = (const float*)d_in[3];
  const float* wo = (const float*)d_in[4];
  const float* fc = (const float*)d_in[5];
  const float* fs = (const float*)d_in[6];

  char* ws = (char*)d_ws;
  u16* xb   = (u16*)(ws);
  u16* wqkv = (u16*)(ws + 16777216);
  u16* wob  = (u16*)(ws + 41943040);
  u16* qkv  = (u16*)(ws + 50331648);
  u16* aout = (u16*)(ws + 100663296);

  cast_f32_bf16<<<8192, 256, 0, stream>>>((const float4*)x, xb, 2097152);
  cast_f32_bf16<<<4096, 256, 0, stream>>>((const float4*)wq, wqkv, 1048576);
  cast_f32_bf16<<<4096, 256, 0, stream>>>((const float4*)wk, wqkv + 4194304, 1048576);
  cast_f32_bf16<<<4096, 256, 0, stream>>>((const float4*)wv, wqkv + 8388608, 1048576);
  cast_f32_bf16<<<4096, 256, 0, stream>>>((const float4*)wo, wob, 1048576);

  gemm_nt_8ph<0><<<384, 512, 0, stream>>>(xb, wqkv, qkv, 4096, 6144, 2048);
  rope_kernel<<<8192, 256, 0, stream>>>(qkv, fc, fs);
  attn_fwd<<<512, 256, 0, stream>>>(qkv, aout);
  gemm_nt<1><<<512, 256, 0, stream>>>(aout, wob, d_out, 4096, 2048, 2048);
}